// Round 1
// baseline (5412.543 us; speedup 1.0000x reference)
//
#include <hip/hip_runtime.h>
#include <hip/hip_bf16.h>
#include <stdint.h>

#define N_NODES 100000
#define IN_F    512
#define OUT_F   256
#define N_EDGES 1600000

typedef __attribute__((ext_vector_type(4))) float f32x4;
typedef __attribute__((ext_vector_type(8))) short bf16x8;

#define BM 128
#define BN 128
#define BK 32
#define LDW (BK + 8)   // pad rows to 40 bf16 (80 B) -> <=2-way bank aliasing (free)

__device__ __forceinline__ float bf2f(uint16_t u) {
    union { uint32_t i; float f; } c; c.i = ((uint32_t)u) << 16; return c.f;
}
__device__ __forceinline__ uint16_t f2bf(float f) {
    union { float f; uint32_t i; } c; c.f = f;
    uint32_t x = c.i;
    return (uint16_t)((x + 0x7FFFu + ((x >> 16) & 1u)) >> 16);  // RNE
}

// h[row][col] = sum_k feat[row][k] * W[col][k] + b[col], stored bf16
__global__ __launch_bounds__(256) void gcn_gemm_kernel(
    const float* __restrict__ feat, const float* __restrict__ W,
    const float* __restrict__ bias, uint16_t* __restrict__ h)
{
    __shared__ uint16_t At[BM][LDW];
    __shared__ uint16_t Bt[BN][LDW];

    const int bid = blockIdx.x;
    const int mt = bid >> 1;          // consecutive blocks share the A panel (L2 reuse)
    const int nt = bid & 1;
    const int m0 = mt * BM;
    const int n0 = nt * BN;

    const int t    = threadIdx.x;
    const int wid  = t >> 6;
    const int lane = t & 63;
    const int wr   = wid >> 1, wc = wid & 1;   // 2x2 wave grid, 64x64 per wave
    const int lrow = lane & 15;                // frag row (A) / col (B, C)
    const int kg   = lane >> 4;                // k-group 0..3

    f32x4 acc[4][4] = {};

    const int srow  = t >> 1;   // staging row 0..127
    const int shalf = t & 1;    // which 16-float half of the 32-float row chunk
    const bool arow_ok = (m0 + srow) < N_NODES;

    const float* gA = feat + (size_t)(m0 + srow) * IN_F + shalf * 16;
    const float* gB = W    + (size_t)(n0 + srow) * IN_F + shalf * 16;

    for (int kt = 0; kt < IN_F / BK; ++kt) {
        // ---- stage A (fp32 -> bf16) ----
        uint16_t ua[16];
        if (arow_ok) {
            const f32x4* p = (const f32x4*)(gA + kt * BK);
            #pragma unroll
            for (int i = 0; i < 4; ++i) {
                f32x4 v = p[i];
                ua[i*4+0] = f2bf(v[0]); ua[i*4+1] = f2bf(v[1]);
                ua[i*4+2] = f2bf(v[2]); ua[i*4+3] = f2bf(v[3]);
            }
        } else {
            #pragma unroll
            for (int i = 0; i < 16; ++i) ua[i] = 0;
        }
        // ---- stage B (W rows; n0+srow < 256 always) ----
        uint16_t ub[16];
        {
            const f32x4* p = (const f32x4*)(gB + kt * BK);
            #pragma unroll
            for (int i = 0; i < 4; ++i) {
                f32x4 v = p[i];
                ub[i*4+0] = f2bf(v[0]); ub[i*4+1] = f2bf(v[1]);
                ub[i*4+2] = f2bf(v[2]); ub[i*4+3] = f2bf(v[3]);
            }
        }
        *(bf16x8*)&At[srow][shalf*16]     = *(bf16x8*)&ua[0];
        *(bf16x8*)&At[srow][shalf*16 + 8] = *(bf16x8*)&ua[8];
        *(bf16x8*)&Bt[srow][shalf*16]     = *(bf16x8*)&ub[0];
        *(bf16x8*)&Bt[srow][shalf*16 + 8] = *(bf16x8*)&ub[8];
        __syncthreads();

        // ---- fragments + MFMA ----
        bf16x8 af[4], bfr[4];
        #pragma unroll
        for (int m = 0; m < 4; ++m)
            af[m] = *(const bf16x8*)&At[wr*64 + m*16 + lrow][kg*8];
        #pragma unroll
        for (int n = 0; n < 4; ++n)
            bfr[n] = *(const bf16x8*)&Bt[wc*64 + n*16 + lrow][kg*8];
        #pragma unroll
        for (int m = 0; m < 4; ++m)
            #pragma unroll
            for (int n = 0; n < 4; ++n)
                acc[m][n] = __builtin_amdgcn_mfma_f32_16x16x32_bf16(
                    af[m], bfr[n], acc[m][n], 0, 0, 0);
        __syncthreads();
    }

    // ---- epilogue: bias + bf16 store ----
    #pragma unroll
    for (int n = 0; n < 4; ++n) {
        const int col = n0 + wc*64 + n*16 + lrow;
        const float bv = bias[col];
        #pragma unroll
        for (int m = 0; m < 4; ++m) {
            #pragma unroll
            for (int j = 0; j < 4; ++j) {
                const int row = m0 + wr*64 + m*16 + kg*4 + j;
                if (row < N_NODES)
                    h[(size_t)row * OUT_F + col] = f2bf(acc[m][n][j] + bv);
            }
        }
    }
}

// one 64-lane wave per edge; 4 feats/lane; atomic sum into out[dst]
__global__ __launch_bounds__(256) void gcn_scatter_kernel(
    const uint16_t* __restrict__ h, const int* __restrict__ src,
    const int* __restrict__ dst, float* __restrict__ out)
{
    const int e = (blockIdx.x << 2) | (threadIdx.x >> 6);
    if (e >= N_EDGES) return;
    const int lane = threadIdx.x & 63;
    const int s = src[e];
    const int d = dst[e];
    const ushort4 v = *((const ushort4*)(h + (size_t)s * OUT_F) + lane);
    float* op = out + (size_t)d * OUT_F + (lane << 2);
    unsafeAtomicAdd(op + 0, bf2f(v.x));
    unsafeAtomicAdd(op + 1, bf2f(v.y));
    unsafeAtomicAdd(op + 2, bf2f(v.z));
    unsafeAtomicAdd(op + 3, bf2f(v.w));
}

extern "C" void kernel_launch(void* const* d_in, const int* in_sizes, int n_in,
                              void* d_out, int out_size, void* d_ws, size_t ws_size,
                              hipStream_t stream) {
    const float* feat = (const float*)d_in[0];
    const float* W    = (const float*)d_in[1];
    const float* bias = (const float*)d_in[2];
    const int*   src  = (const int*)d_in[3];
    const int*   dst  = (const int*)d_in[4];
    float*       out  = (float*)d_out;
    uint16_t*    h    = (uint16_t*)d_ws;   // 100000*256 bf16 = 51.2 MB

    hipMemsetAsync(out, 0, (size_t)out_size * sizeof(float), stream);

    const int mtiles = (N_NODES + BM - 1) / BM;  // 782
    gcn_gemm_kernel<<<mtiles * 2, 256, 0, stream>>>(feat, W, bias, h);

    gcn_scatter_kernel<<<(N_EDGES + 3) / 4, 256, 0, stream>>>(h, src, dst, out);
}

// Round 2
// 453.995 us; speedup vs baseline: 11.9220x; 11.9220x over previous
//
#include <hip/hip_runtime.h>
#include <hip/hip_bf16.h>
#include <stdint.h>

#define N_NODES 100000
#define IN_F    512
#define OUT_F   256
#define N_EDGES 1600000

typedef __attribute__((ext_vector_type(4))) float f32x4;
typedef __attribute__((ext_vector_type(8))) short bf16x8;

#define BM 128
#define BN 128
#define BK 32
#define LDW (BK + 8)

#define SCAN_CHUNK 4096
#define NCHUNKS ((N_NODES + SCAN_CHUNK - 1) / SCAN_CHUNK)   // 25

__device__ __forceinline__ float bf2f(uint16_t u) {
    union { uint32_t i; float f; } c; c.i = ((uint32_t)u) << 16; return c.f;
}
__device__ __forceinline__ uint16_t f2bf(float f) {
    union { float f; uint32_t i; } c; c.f = f;
    uint32_t x = c.i;
    return (uint16_t)((x + 0x7FFFu + ((x >> 16) & 1u)) >> 16);  // RNE
}

// ---------------- GEMM: h = bf16(feat @ W^T + b) ----------------
__global__ __launch_bounds__(256) void gcn_gemm_kernel(
    const float* __restrict__ feat, const float* __restrict__ W,
    const float* __restrict__ bias, uint16_t* __restrict__ h)
{
    __shared__ uint16_t At[BM][LDW];
    __shared__ uint16_t Bt[BN][LDW];

    const int bid = blockIdx.x;
    const int mt = bid >> 1;
    const int nt = bid & 1;
    const int m0 = mt * BM;
    const int n0 = nt * BN;

    const int t    = threadIdx.x;
    const int wid  = t >> 6;
    const int lane = t & 63;
    const int wr   = wid >> 1, wc = wid & 1;
    const int lrow = lane & 15;
    const int kg   = lane >> 4;

    f32x4 acc[4][4] = {};

    const int srow  = t >> 1;
    const int shalf = t & 1;
    const bool arow_ok = (m0 + srow) < N_NODES;

    const float* gA = feat + (size_t)(m0 + srow) * IN_F + shalf * 16;
    const float* gB = W    + (size_t)(n0 + srow) * IN_F + shalf * 16;

    for (int kt = 0; kt < IN_F / BK; ++kt) {
        uint16_t ua[16];
        if (arow_ok) {
            const f32x4* p = (const f32x4*)(gA + kt * BK);
            #pragma unroll
            for (int i = 0; i < 4; ++i) {
                f32x4 v = p[i];
                ua[i*4+0] = f2bf(v[0]); ua[i*4+1] = f2bf(v[1]);
                ua[i*4+2] = f2bf(v[2]); ua[i*4+3] = f2bf(v[3]);
            }
        } else {
            #pragma unroll
            for (int i = 0; i < 16; ++i) ua[i] = 0;
        }
        uint16_t ub[16];
        {
            const f32x4* p = (const f32x4*)(gB + kt * BK);
            #pragma unroll
            for (int i = 0; i < 4; ++i) {
                f32x4 v = p[i];
                ub[i*4+0] = f2bf(v[0]); ub[i*4+1] = f2bf(v[1]);
                ub[i*4+2] = f2bf(v[2]); ub[i*4+3] = f2bf(v[3]);
            }
        }
        *(bf16x8*)&At[srow][shalf*16]     = *(bf16x8*)&ua[0];
        *(bf16x8*)&At[srow][shalf*16 + 8] = *(bf16x8*)&ua[8];
        *(bf16x8*)&Bt[srow][shalf*16]     = *(bf16x8*)&ub[0];
        *(bf16x8*)&Bt[srow][shalf*16 + 8] = *(bf16x8*)&ub[8];
        __syncthreads();

        bf16x8 af[4], bfr[4];
        #pragma unroll
        for (int m = 0; m < 4; ++m)
            af[m] = *(const bf16x8*)&At[wr*64 + m*16 + lrow][kg*8];
        #pragma unroll
        for (int n = 0; n < 4; ++n)
            bfr[n] = *(const bf16x8*)&Bt[wc*64 + n*16 + lrow][kg*8];
        #pragma unroll
        for (int m = 0; m < 4; ++m)
            #pragma unroll
            for (int n = 0; n < 4; ++n)
                acc[m][n] = __builtin_amdgcn_mfma_f32_16x16x32_bf16(
                    af[m], bfr[n], acc[m][n], 0, 0, 0);
        __syncthreads();
    }

    #pragma unroll
    for (int n = 0; n < 4; ++n) {
        const int col = n0 + wc*64 + n*16 + lrow;
        const float bv = bias[col];
        #pragma unroll
        for (int m = 0; m < 4; ++m) {
            #pragma unroll
            for (int j = 0; j < 4; ++j) {
                const int row = m0 + wr*64 + m*16 + kg*4 + j;
                if (row < N_NODES)
                    h[(size_t)row * OUT_F + col] = f2bf(acc[m][n][j] + bv);
            }
        }
    }
}

// ---------------- CSR build ----------------
__global__ __launch_bounds__(256) void hist_kernel(
    const int* __restrict__ dst, int* __restrict__ deg)
{
    const int e = blockIdx.x * 256 + threadIdx.x;
    if (e < N_EDGES) atomicAdd(&deg[dst[e]], 1);
}

__global__ __launch_bounds__(256) void chunk_reduce_kernel(
    const int* __restrict__ deg, int* __restrict__ chunkSum)
{
    __shared__ int red[256];
    const int b = blockIdx.x, t = threadIdx.x;
    const int base = b * SCAN_CHUNK;
    int s = 0;
    #pragma unroll
    for (int i = 0; i < 16; ++i) {
        const int idx = base + t * 16 + i;
        s += (idx < N_NODES) ? deg[idx] : 0;
    }
    red[t] = s;
    __syncthreads();
    for (int off = 128; off > 0; off >>= 1) {
        if (t < off) red[t] += red[t + off];
        __syncthreads();
    }
    if (t == 0) chunkSum[b] = red[0];
}

__global__ void scan_chunksums_kernel(const int* __restrict__ chunkSum,
                                      int* __restrict__ chunkOff)
{
    if (threadIdx.x == 0 && blockIdx.x == 0) {
        int acc = 0;
        for (int i = 0; i < NCHUNKS; ++i) { chunkOff[i] = acc; acc += chunkSum[i]; }
    }
}

__global__ __launch_bounds__(256) void chunk_scan_kernel(
    const int* __restrict__ deg, const int* __restrict__ chunkOff,
    int* __restrict__ start, int* __restrict__ cursor)
{
    __shared__ int tsum[256];
    const int b = blockIdx.x, t = threadIdx.x;
    const int base = b * SCAN_CHUNK;
    int vals[16];
    int s = 0;
    #pragma unroll
    for (int i = 0; i < 16; ++i) {
        const int idx = base + t * 16 + i;
        const int v = (idx < N_NODES) ? deg[idx] : 0;
        vals[i] = s;            // exclusive within-thread prefix
        s += v;
    }
    int x = s;
    tsum[t] = x;
    __syncthreads();
    #pragma unroll
    for (int off = 1; off < 256; off <<= 1) {
        const int y = (t >= off) ? tsum[t - off] : 0;
        __syncthreads();
        x += y;
        tsum[t] = x;
        __syncthreads();
    }
    const int thread_off = chunkOff[b] + (t == 0 ? 0 : tsum[t - 1]);
    #pragma unroll
    for (int i = 0; i < 16; ++i) {
        const int idx = base + t * 16 + i;
        if (idx < N_NODES) {
            const int st = thread_off + vals[i];
            start[idx] = st;
            cursor[idx] = st;
        }
    }
}

__global__ __launch_bounds__(256) void csr_fill_kernel(
    const int* __restrict__ src, const int* __restrict__ dst,
    int* __restrict__ cursor, int* __restrict__ csr_src)
{
    const int e = blockIdx.x * 256 + threadIdx.x;
    if (e < N_EDGES) {
        const int d = dst[e];
        const int p = atomicAdd(&cursor[d], 1);
        csr_src[p] = src[e];
    }
}

// ---------------- gather: one wave per dst node, atomic-free ----------------
__global__ __launch_bounds__(256) void gcn_gather_kernel(
    const uint16_t* __restrict__ h, const int* __restrict__ start,
    const int* __restrict__ csr_src, float* __restrict__ out)
{
    const int n = blockIdx.x * 4 + (threadIdx.x >> 6);
    if (n >= N_NODES) return;
    const int lane = threadIdx.x & 63;
    const int beg = start[n];
    const int end = (n == N_NODES - 1) ? N_EDGES : start[n + 1];

    float a0 = 0.f, a1 = 0.f, a2 = 0.f, a3 = 0.f;
    int j = beg;
    for (; j + 1 < end; j += 2) {
        const int s0 = csr_src[j];
        const int s1 = csr_src[j + 1];
        const ushort4 v0 = *((const ushort4*)(h + (size_t)s0 * OUT_F) + lane);
        const ushort4 v1 = *((const ushort4*)(h + (size_t)s1 * OUT_F) + lane);
        a0 += bf2f(v0.x); a1 += bf2f(v0.y); a2 += bf2f(v0.z); a3 += bf2f(v0.w);
        a0 += bf2f(v1.x); a1 += bf2f(v1.y); a2 += bf2f(v1.z); a3 += bf2f(v1.w);
    }
    if (j < end) {
        const int s0 = csr_src[j];
        const ushort4 v0 = *((const ushort4*)(h + (size_t)s0 * OUT_F) + lane);
        a0 += bf2f(v0.x); a1 += bf2f(v0.y); a2 += bf2f(v0.z); a3 += bf2f(v0.w);
    }
    f32x4 o; o[0] = a0; o[1] = a1; o[2] = a2; o[3] = a3;
    *((f32x4*)(out + (size_t)n * OUT_F) + lane) = o;
}

// ---------------- fallback atomic scatter (small ws) ----------------
__global__ __launch_bounds__(256) void gcn_scatter_kernel(
    const uint16_t* __restrict__ h, const int* __restrict__ src,
    const int* __restrict__ dst, float* __restrict__ out)
{
    const int e = (blockIdx.x << 2) | (threadIdx.x >> 6);
    if (e >= N_EDGES) return;
    const int lane = threadIdx.x & 63;
    const int s = src[e];
    const int d = dst[e];
    const ushort4 v = *((const ushort4*)(h + (size_t)s * OUT_F) + lane);
    float* op = out + (size_t)d * OUT_F + (lane << 2);
    unsafeAtomicAdd(op + 0, bf2f(v.x));
    unsafeAtomicAdd(op + 1, bf2f(v.y));
    unsafeAtomicAdd(op + 2, bf2f(v.z));
    unsafeAtomicAdd(op + 3, bf2f(v.w));
}

static inline size_t align256(size_t x) { return (x + 255) & ~(size_t)255; }

extern "C" void kernel_launch(void* const* d_in, const int* in_sizes, int n_in,
                              void* d_out, int out_size, void* d_ws, size_t ws_size,
                              hipStream_t stream) {
    const float* feat = (const float*)d_in[0];
    const float* W    = (const float*)d_in[1];
    const float* bias = (const float*)d_in[2];
    const int*   src  = (const int*)d_in[3];
    const int*   dst  = (const int*)d_in[4];
    float*       out  = (float*)d_out;

    char* ws = (char*)d_ws;
    size_t off = 0;
    uint16_t* h = (uint16_t*)(ws + off);        off = align256(off + (size_t)N_NODES * OUT_F * 2);
    int* deg      = (int*)(ws + off);           off = align256(off + (size_t)N_NODES * 4);
    int* start    = (int*)(ws + off);           off = align256(off + (size_t)N_NODES * 4);
    int* cursor   = (int*)(ws + off);           off = align256(off + (size_t)N_NODES * 4);
    int* chunkSum = (int*)(ws + off);           off = align256(off + (size_t)NCHUNKS * 4);
    int* chunkOff = (int*)(ws + off);           off = align256(off + (size_t)NCHUNKS * 4);
    int* csr_src  = (int*)(ws + off);           off = align256(off + (size_t)N_EDGES * 4);
    const bool csr_ok = (off <= ws_size);

    const int mtiles = (N_NODES + BM - 1) / BM;  // 782
    gcn_gemm_kernel<<<mtiles * 2, 256, 0, stream>>>(feat, W, bias, h);

    if (csr_ok) {
        hipMemsetAsync(deg, 0, (size_t)N_NODES * 4, stream);
        const int eblocks = (N_EDGES + 255) / 256;  // 6250
        hist_kernel<<<eblocks, 256, 0, stream>>>(dst, deg);
        chunk_reduce_kernel<<<NCHUNKS, 256, 0, stream>>>(deg, chunkSum);
        scan_chunksums_kernel<<<1, 64, 0, stream>>>(chunkSum, chunkOff);
        chunk_scan_kernel<<<NCHUNKS, 256, 0, stream>>>(deg, chunkOff, start, cursor);
        csr_fill_kernel<<<eblocks, 256, 0, stream>>>(src, dst, cursor, csr_src);
        gcn_gather_kernel<<<(N_NODES + 3) / 4, 256, 0, stream>>>(h, start, csr_src, out);
    } else {
        hipMemsetAsync(out, 0, (size_t)out_size * sizeof(float), stream);
        gcn_scatter_kernel<<<(N_EDGES + 3) / 4, 256, 0, stream>>>(h, src, dst, out);
    }
}